// Round 5
// baseline (2977.850 us; speedup 1.0000x reference)
//
#include <hip/hip_runtime.h>
#include <hip/hip_fp16.h>

// GNN: 3x GCNConv (25->64->64->32) + global mean pool (256 graphs) + MLP head.
// Round 10: scatter-into-LDS phased aggregation.
// History: R7 plain gather = fetch-path-bound (315MB @3.4TB/s, 102us F=64).
// R8 src-range phasing hit compulsory fetch (130MB) but died on latency
// (4-edge segments, 195us). R9 lockstep predication restored MLP but paid
// max-of-K = 2x fetch (262MB, 171us). R10: block owns 128 dst nodes with an
// fp32 accumulator tile in LDS; edges sorted by (src-range, dst_local) so
// each (block,range) is ONE contiguous ~512-edge segment swept flat with
// unroll-4 slots (F/2 lanes per edge) and ds_add_f32 into LDS. Zero
// predication waste, ~128 loads in flight/CU, 2MB/range L2 window kept.
// fp16 payload; fp32 accumulation. Assumes N < 2^17 (17-bit src packing).

#define IN_DIM 25
#define HID 64
#define OUT3 32
#define BK_LOG 7
#define BK_NODES 128
#define MAXB 1024
#define EPB1 16384
#define BCAP 8192
#define RNG_LOG 14      // src-range = src >> 14  (8 ranges cover N < 131072)
#define NR 8
#define NKEY (BK_NODES * NR)

__device__ inline int ld_nt_i32(const int* p) {
    return __builtin_nontemporal_load(p);
}

// ---------------- stage 1: bucket histogram (LDS-privatized) ----------------
__global__ __launch_bounds__(256) void bucket_hist(const int* __restrict__ dst,
                                                   int* __restrict__ bhist, int nE) {
    __shared__ int h[MAXB];
    for (int i = threadIdx.x; i < MAXB; i += 256) h[i] = 0;
    __syncthreads();
    int e0 = blockIdx.x * 8192;
    int cnt = min(8192, nE - e0);
    for (int i = threadIdx.x; i < cnt; i += 256)
        atomicAdd(&h[(unsigned)dst[e0 + i] >> BK_LOG], 1);
    __syncthreads();
    for (int i = threadIdx.x; i < MAXB; i += 256)
        if (h[i]) atomicAdd(&bhist[i], h[i]);
}

// ---------------- stage 2: scan bucket counts (1 block) ----------------
__global__ __launch_bounds__(256) void bucket_scan(const int* __restrict__ bhist,
                                                   int* __restrict__ bbase,
                                                   int* __restrict__ cursor,
                                                   int nb, int nE) {
    __shared__ int s4[256];
    int t = threadIdx.x;
    int v[4]; int sum = 0;
#pragma unroll
    for (int j = 0; j < 4; ++j) {
        int b = 4 * t + j;
        v[j] = (b < nb) ? bhist[b] : 0;
        sum += v[j];
    }
    s4[t] = sum;
    __syncthreads();
    for (int off = 1; off < 256; off <<= 1) {
        int mine = s4[t];
        int add = (t >= off) ? s4[t - off] : 0;
        __syncthreads();
        s4[t] = mine + add;
        __syncthreads();
    }
    int run = s4[t] - sum;
#pragma unroll
    for (int j = 0; j < 4; ++j) {
        int b = 4 * t + j;
        if (b < nb) { bbase[b] = run; cursor[b] = run; }
        run += v[j];
    }
    if (t == 0) bbase[nb] = nE;
}

// ---------------- stage 3: partition edges into buckets (coalesced) --------
__global__ __launch_bounds__(256) void partition_kernel(
        const int* __restrict__ src, const int* __restrict__ dst,
        int* __restrict__ cursor, unsigned int* __restrict__ ebuf, int nE) {
    __shared__ int lh[MAXB];
    __shared__ int lrun[MAXB];
    __shared__ int lcur[MAXB];
    __shared__ int swp[256];
    __shared__ unsigned int stg[EPB1];
    __shared__ unsigned short sbk[EPB1];
    int t = threadIdx.x;
    int e0 = blockIdx.x * EPB1;
    int cnt = min(EPB1, nE - e0);
    for (int i = t; i < MAXB; i += 256) lh[i] = 0;
    __syncthreads();
    for (int i = t; i < cnt; i += 256)
        atomicAdd(&lh[(unsigned)dst[e0 + i] >> BK_LOG], 1);
    __syncthreads();
    int v[4]; int sum = 0;
#pragma unroll
    for (int j = 0; j < 4; ++j) { v[j] = lh[4 * t + j]; sum += v[j]; }
    swp[t] = sum;
    __syncthreads();
    for (int off = 1; off < 256; off <<= 1) {
        int mine = swp[t];
        int add = (t >= off) ? swp[t - off] : 0;
        __syncthreads();
        swp[t] = mine + add;
        __syncthreads();
    }
    int run = swp[t] - sum;
#pragma unroll
    for (int j = 0; j < 4; ++j) {
        int b = 4 * t + j;
        lh[b] = run;
        lcur[b] = 0;
        if (v[j] > 0) lrun[b] = atomicAdd(&cursor[b], v[j]);
        run += v[j];
    }
    __syncthreads();
    for (int i = t; i < cnt; i += 256) {
        int d = dst[e0 + i];
        int s = src[e0 + i];
        int b = (unsigned)d >> BK_LOG;
        int lp = atomicAdd(&lcur[b], 1);
        int slot = lh[b] + lp;
        stg[slot] = ((unsigned)(d & (BK_NODES - 1)) << 17) | (unsigned)s;
        sbk[slot] = (unsigned short)b;
    }
    __syncthreads();
    for (int i = t; i < cnt; i += 256) {
        int b = sbk[i];
        int g = lrun[b] + (i - lh[b]);
        ebuf[g] = stg[i];
    }
}

// ---- stage 4: per-bucket sort by (src-range, dst_local) + rbase + dinv ----
// rbase[b*9 + r] = start of (block b, range r) segment; rbase[b*9+8] = end.
// Edge words keep full (dst_local << 17) | src payload.
__global__ __launch_bounds__(256) void bucket_csr_kernel(
        unsigned int* __restrict__ ebuf, const int* __restrict__ bbase,
        float* __restrict__ dinv, int* __restrict__ rbase, int nN) {
    int b = blockIdx.x;
    int node_lo = b << BK_LOG;
    int nn = min(BK_NODES, nN - node_lo);
    int base = bbase[b];
    int cnt = bbase[b + 1] - base;
    if (cnt > BCAP) cnt = BCAP;
    __shared__ unsigned int in[BCAP];
    __shared__ unsigned int outb[BCAP];
    __shared__ int h[NKEY], sc[NKEY], lc[NKEY];
    __shared__ int swp[256];
    int t = threadIdx.x;
    for (int i = t; i < cnt; i += 256) in[i] = ebuf[base + i];
    for (int i = t; i < NKEY; i += 256) { h[i] = 0; lc[i] = 0; }
    __syncthreads();
    for (int i = t; i < cnt; i += 256) {
        unsigned int w = in[i];
        int kk = (int)(((w & 0x1FFFFu) >> RNG_LOG) << BK_LOG) | (int)(w >> 17);
        atomicAdd(&h[kk], 1);
    }
    __syncthreads();
    int v[4]; int sum = 0;
#pragma unroll
    for (int j = 0; j < 4; ++j) { v[j] = h[4 * t + j]; sum += v[j]; }
    swp[t] = sum;
    __syncthreads();
    for (int off = 1; off < 256; off <<= 1) {
        int mine = swp[t];
        int add = (t >= off) ? swp[t - off] : 0;
        __syncthreads();
        swp[t] = mine + add;
        __syncthreads();
    }
    int run = swp[t] - sum;
#pragma unroll
    for (int j = 0; j < 4; ++j) { sc[4 * t + j] = run; run += v[j]; }
    __syncthreads();
    // per-(block,range) segment starts
    if (t < NR) rbase[b * (NR + 1) + t] = base + sc[t << BK_LOG];
    if (t == 0) rbase[b * (NR + 1) + NR] = base + cnt;
    // per-node degree -> dinv
    if (t < nn) {
        int deg = 0;
#pragma unroll
        for (int r = 0; r < NR; ++r) deg += h[(r << BK_LOG) | t];
        dinv[node_lo + t] = rsqrtf((float)deg + 1.0f);
    }
    __syncthreads();
    for (int i = t; i < cnt; i += 256) {
        unsigned int w = in[i];
        int kk = (int)(((w & 0x1FFFFu) >> RNG_LOG) << BK_LOG) | (int)(w >> 17);
        int lp = atomicAdd(&lc[kk], 1);
        outb[sc[kk] + lp] = w;   // keep full payload
    }
    __syncthreads();
    for (int i = t; i < cnt; i += 256) ebuf[base + i] = outb[i];
}

// ---------------- pad + pre-scale helpers ----------------
// xp[node][c] = half( x[node][c] * dinv[node] )  (pre-scaled gather operand)
__global__ void padx_kernel(const float* __restrict__ x, const float* __restrict__ dinv,
                            __half* __restrict__ xp, int n) {
    int i = blockIdx.x * 256 + threadIdx.x;   // one thread per 2 cols
    if (i < n * 16) {
        int node = i >> 4, c2 = (i & 15) * 2;
        float s = dinv[node];
        float v0 = (c2     < IN_DIM) ? x[(size_t)node * IN_DIM + c2    ] * s : 0.f;
        float v1 = (c2 + 1 < IN_DIM) ? x[(size_t)node * IN_DIM + c2 + 1] * s : 0.f;
        *(__half2*)&xp[(size_t)node * 32 + c2] = __floats2half2_rn(v0, v1);
    }
}

__global__ void padw_kernel(const float* __restrict__ W1, float* __restrict__ W1p) {
    int i = blockIdx.x * 256 + threadIdx.x;
    if (i < 32 * HID) {
        int r = i >> 6, c = i & 63;
        W1p[i] = (r < IN_DIM) ? W1[r * HID + c] : 0.f;
    }
}

// ---------------- dense layer: out = in @ W [*dinv->half] [+bias,relu] -----
// SCALE=true writes __half (gather operand); SCALE=false writes float.
template<int INF, int OUTF, bool ACT, bool SCALE>
__global__ __launch_bounds__(256) void gemm_kernel(
        const float* __restrict__ in, const float* __restrict__ W,
        const float* __restrict__ bias, const float* __restrict__ dinv,
        void* __restrict__ out, int n) {
    constexpr int TPN = OUTF / 4;
    constexpr int NPB = 256 / TPN;
    constexpr int LDK = INF + 4;
    __shared__ float sW[INF * OUTF];
    __shared__ float sIn[NPB][LDK];
    for (int i = threadIdx.x; i < INF * OUTF; i += 256) sW[i] = W[i];
    int node0 = blockIdx.x * NPB;
    for (int i = threadIdx.x; i < NPB * INF; i += 256) {
        int ln = i / INF, k = i % INF;
        int node = node0 + ln;
        sIn[ln][k] = (node < n) ? in[(size_t)node * INF + k] : 0.f;
    }
    __syncthreads();
    int g   = threadIdx.x / TPN;
    int of0 = (threadIdx.x % TPN) * 4;
    int node = node0 + g;
    float4 acc = make_float4(0.f, 0.f, 0.f, 0.f);
#pragma unroll
    for (int k = 0; k < INF; ++k) {
        float aj = sIn[g][k];
        const float4 wv = *(const float4*)&sW[k * OUTF + of0];
        acc.x += aj * wv.x; acc.y += aj * wv.y;
        acc.z += aj * wv.z; acc.w += aj * wv.w;
    }
    if (ACT) {
        const float4 bv = *(const float4*)&bias[of0];
        acc.x = fmaxf(acc.x + bv.x, 0.f);
        acc.y = fmaxf(acc.y + bv.y, 0.f);
        acc.z = fmaxf(acc.z + bv.z, 0.f);
        acc.w = fmaxf(acc.w + bv.w, 0.f);
    }
    if (node < n) {
        if (SCALE) {
            float s = dinv[node];
            union { __half2 h[2]; uint2 u; } pk;
            pk.h[0] = __floats2half2_rn(acc.x * s, acc.y * s);
            pk.h[1] = __floats2half2_rn(acc.z * s, acc.w * s);
            *(uint2*)((__half*)out + (size_t)node * OUTF + of0) = pk.u;
        } else {
            *(float4*)((float*)out + (size_t)node * OUTF + of0) = acc;
        }
    }
}

// ---------- scatter-into-LDS phased aggregation on fp16 rows ----------
// Block b owns 128 dst nodes; fp32 acc tile in LDS (row pad +1 float for
// bank-parity mixing). For each src-range r: sweep the contiguous
// (block, range) edge segment; slot (= F/2 lanes) per edge, unroll 4;
// ds_add_f32 accumulate. Epilogue: *dinv, +bias, relu, coalesced NT store.
template<int F, bool ACT>
__global__ __launch_bounds__(256) void gather_kernel(
        const __half* __restrict__ hp, const float* __restrict__ dinv,
        const int* __restrict__ rbase, const unsigned int* __restrict__ ebuf,
        const float* __restrict__ bias, float* __restrict__ agg, int n) {
    constexpr int LPE = F / 2;          // lanes per edge (half2 each)
    constexpr int NSLOT = 256 / LPE;    // edge slots per block
    constexpr int LDA = F + 1;          // padded LDS row (floats)
    constexpr int U = 4;
    __shared__ float acc[BK_NODES * LDA];
    int b = blockIdx.x, t = threadIdx.x;
    int node_lo = b << BK_LOG;
    // init with self-loop row (pre-scaled); zero for OOB nodes
    for (int i = t; i < BK_NODES * LPE; i += 256) {
        int ln = i / LPE, c2 = (i % LPE) * 2;
        int node = node_lo + ln;
        float2 v = make_float2(0.f, 0.f);
        if (node < n)
            v = __half22float2(*(const __half2*)&hp[(size_t)node * F + c2]);
        acc[ln * LDA + c2] = v.x;
        acc[ln * LDA + c2 + 1] = v.y;
    }
    __syncthreads();
    int slot = t / LPE;
    int f2   = (t % LPE) * 2;
    for (int r = 0; r < NR; ++r) {
        int s  = rbase[b * (NR + 1) + r];
        int e1 = rbase[b * (NR + 1) + r + 1];
        for (int e0 = s; e0 < e1; e0 += NSLOT * U) {
            int e = e0 + slot * U;
            unsigned int w[U];
            float2 v[U];
#pragma unroll
            for (int u = 0; u < U; ++u)
                w[u] = (e + u < e1) ? ebuf[e + u] : 0xFFFFFFFFu;
#pragma unroll
            for (int u = 0; u < U; ++u) {
                v[u] = make_float2(0.f, 0.f);
                if (w[u] != 0xFFFFFFFFu)
                    v[u] = __half22float2(
                        *(const __half2*)&hp[(size_t)(w[u] & 0x1FFFFu) * F + f2]);
            }
#pragma unroll
            for (int u = 0; u < U; ++u) {
                if (w[u] != 0xFFFFFFFFu) {
                    int dl = (int)(w[u] >> 17);
                    atomicAdd(&acc[dl * LDA + f2],     v[u].x);
                    atomicAdd(&acc[dl * LDA + f2 + 1], v[u].y);
                }
            }
        }
        __syncthreads();   // keep the block's waves range-phased
    }
    // epilogue: scale, bias, relu, store
    for (int i = t; i < BK_NODES * LPE; i += 256) {
        int ln = i / LPE, c2 = (i % LPE) * 2;
        int node = node_lo + ln;
        if (node < n) {
            float s = dinv[node];
            float rx = acc[ln * LDA + c2] * s;
            float ry = acc[ln * LDA + c2 + 1] * s;
            if (ACT) {
                rx = fmaxf(rx + bias[c2], 0.f);
                ry = fmaxf(ry + bias[c2 + 1], 0.f);
            }
            union { float2 f; unsigned long long u; } o;
            o.f = make_float2(rx, ry);
            __builtin_nontemporal_store(o.u,
                (unsigned long long*)&agg[(size_t)node * F + c2]);
        }
    }
}

// ---------------- mean pool ----------------
__global__ __launch_bounds__(256) void pool_kernel(
        const float* __restrict__ h3, const int* __restrict__ batch,
        int n, float* __restrict__ pool) {
    int g = blockIdx.x;
    int lo = 0, hi = n;
    while (lo < hi) { int m = (lo + hi) >> 1; if (batch[m] < g) lo = m + 1; else hi = m; }
    int s = lo;
    hi = n;
    while (lo < hi) { int m = (lo + hi) >> 1; if (batch[m] < g + 1) lo = m + 1; else hi = m; }
    int e = lo;
    constexpr int F = OUT3;
    int ln = threadIdx.x / F;
    int f  = threadIdx.x % F;
    float acc = 0.f;
    for (int i = s + ln; i < e; i += 8)
        acc += h3[(size_t)i * F + f];
    __shared__ float red[8][F];
    red[ln][f] = acc;
    __syncthreads();
    if (ln == 0) {
        float t = 0.f;
#pragma unroll
        for (int j = 0; j < 8; ++j) t += red[j][f];
        float cnt = (float)((e - s) > 0 ? (e - s) : 1);
        pool[g * F + f] = t / cnt;
    }
}

// ---------------- head ----------------
__global__ __launch_bounds__(256) void head_kernel(
        const float* __restrict__ pool, const float* __restrict__ Wh1,
        const float* __restrict__ bh1, const float* __restrict__ Wh2,
        const float* __restrict__ bh2, float* __restrict__ out) {
    __shared__ float sW1[32 * 32];
    __shared__ float sb1[32];
    __shared__ float sW2[32];
    int t = threadIdx.x;
    for (int i = t; i < 1024; i += 256) sW1[i] = Wh1[i];
    if (t < 32) { sb1[t] = bh1[t]; sW2[t] = Wh2[t]; }
    __syncthreads();
    int g = t;
    float y = bh2[0];
    const float* p = &pool[g * 32];
#pragma unroll 4
    for (int j = 0; j < 32; ++j) {
        float a = sb1[j];
#pragma unroll
        for (int k = 0; k < 32; ++k) a += p[k] * sW1[k * 32 + j];
        y += fmaxf(a, 0.f) * sW2[j];
    }
    out[g] = y;
}

extern "C" void kernel_launch(void* const* d_in, const int* in_sizes, int n_in,
                              void* d_out, int out_size, void* d_ws, size_t ws_size,
                              hipStream_t stream) {
    const float* x    = (const float*)d_in[0];
    const int*   ei   = (const int*)  d_in[1];
    const int*   batch= (const int*)  d_in[2];
    const float* W1   = (const float*)d_in[3];
    const float* b1   = (const float*)d_in[4];
    const float* W2   = (const float*)d_in[5];
    const float* b2   = (const float*)d_in[6];
    const float* W3   = (const float*)d_in[7];
    const float* b3   = (const float*)d_in[8];
    const float* Wh1  = (const float*)d_in[9];
    const float* bh1  = (const float*)d_in[10];
    const float* Wh2  = (const float*)d_in[11];
    const float* bh2  = (const float*)d_in[12];
    float* out = (float*)d_out;

    const int N = in_sizes[0] / IN_DIM;
    const int E = in_sizes[1] / 2;
    const int* src = ei;
    const int* dst = ei + E;
    const int NB = (N + BK_NODES - 1) >> BK_LOG;

    // workspace layout (all 4B elements; half buffers alias the fp32 ones)
    char* base = (char*)d_ws;
    unsigned int* ebuf = (unsigned int*)base;       base += (size_t)E * 4;
    int*   bhist   = (int*)base;                    base += (size_t)MAXB * 4;
    int*   bbase   = (int*)base;                    base += (size_t)(MAXB + 1) * 4;
    int*   cursor  = (int*)base;                    base += (size_t)MAXB * 4;
    int*   rbase   = (int*)base;                    base += (size_t)(MAXB * (NR + 1)) * 4;
    float* dinv    = (float*)base;                  base += (size_t)N * 4;
    float* W1p     = (float*)base;                  base += (size_t)32 * HID * 4;
    float* bufA    = (float*)base;                  base += (size_t)N * HID * 4;
    float* bufB    = (float*)base;                  base += (size_t)N * HID * 4;
    float* pool    = (float*)base;

    // ---- CSR build (counting sort; buckets sorted by (range, dst_local)) ----
    hipMemsetAsync(bhist, 0, (size_t)MAXB * sizeof(int), stream);
    bucket_hist<<<(E + 8191) / 8192, 256, 0, stream>>>(dst, bhist, E);
    bucket_scan<<<1, 256, 0, stream>>>(bhist, bbase, cursor, NB, E);
    partition_kernel<<<(E + EPB1 - 1) / EPB1, 256, 0, stream>>>(src, dst, cursor, ebuf, E);
    bucket_csr_kernel<<<NB, 256, 0, stream>>>(ebuf, bbase, dinv, rbase, N);

    // ---- layer 1 (reordered): aggX = A_hat Xp' ; h1 = relu(aggX @ W1p + b1)
    // xp (half) in bufB; aggX (fp32) in bufA; h1 (fp32) back in bufB.
    padx_kernel<<<((size_t)N * 16 + 255) / 256, 256, 0, stream>>>(x, dinv, (__half*)bufB, N);
    padw_kernel<<<(32 * HID + 255) / 256, 256, 0, stream>>>(W1, W1p);
    gather_kernel<32, false><<<NB, 256, 0, stream>>>((const __half*)bufB, dinv, rbase, ebuf, nullptr, bufA, N);
    gemm_kernel<32, HID, true, false><<<(N + 15) / 16, 256, 0, stream>>>(bufA, W1p, b1, nullptr, bufB, N);

    // ---- layer 2: t2' = half((h1 @ W2)*dinv) ; h2 = relu(dinv*(sum t2') + b2)
    gemm_kernel<HID, HID, false, true><<<(N + 15) / 16, 256, 0, stream>>>(bufB, W2, nullptr, dinv, bufA, N);
    gather_kernel<HID, true><<<NB, 256, 0, stream>>>((const __half*)bufA, dinv, rbase, ebuf, b2, bufB, N);

    // ---- layer 3: t3' = half((h2 @ W3)*dinv) ; h3 = relu(dinv*(sum t3') + b3)
    gemm_kernel<HID, OUT3, false, true><<<(N + 31) / 32, 256, 0, stream>>>(bufB, W3, nullptr, dinv, bufA, N);
    gather_kernel<OUT3, true><<<NB, 256, 0, stream>>>((const __half*)bufA, dinv, rbase, ebuf, b3, bufB, N);

    // ---- pool + head ----
    pool_kernel<<<256, 256, 0, stream>>>(bufB, batch, N, pool);
    head_kernel<<<1, 256, 0, stream>>>(pool, Wh1, bh1, Wh2, bh2, out);
}

// Round 6
// 518.064 us; speedup vs baseline: 5.7480x; 5.7480x over previous
//
#include <hip/hip_runtime.h>
#include <hip/hip_fp16.h>

// GNN: 3x GCNConv (25->64->64->32) + global mean pool (256 graphs) + MLP head.
// Round 11: phased streaming gather with register accumulation + LDS flush.
// Lessons: R7 plain gather = fetch-bound (315MB, 102us F=64). R8 phasing hit
// compulsory fetch (130MB) but 4-edge segments died on latency. R9 lockstep
// predication = max-of-K 2x fetch. R10 scatter-LDS-atomics = same-address
// serialization (consecutive edges share dst after (range,dst) sort).
// R11: edges sorted by (range, dst_local) per 128-node bucket. Each lane-
// group (F/2 lanes) owns K nodes; its (range, chunk) edges are ONE contiguous
// dst-sorted run, swept flat with unroll-8 (loads consumed in issue order,
// no padding). Register float2 accumulator; non-atomic LDS row flush only at
// dst boundaries (~every 4 edges); dummy row 128 absorbs +0 flushes. Groups
// own disjoint rows -> no atomics. Per-range barrier keeps the resident
// 782-block grid phased (2MB hp window per range fits per-XCD L2).
// fp16 payload, fp32 accumulation. Assumes N < 2^17 (17-bit src packing).

#define IN_DIM 25
#define HID 64
#define OUT3 32
#define BK_LOG 7
#define BK_NODES 128
#define MAXB 1024
#define EPB1 16384
#define BCAP 8192
#define RNG_LOG 14      // src-range = src >> 14  (8 ranges cover N < 131072)
#define NR 8
#define NKEY (BK_NODES * NR)

// ---------------- stage 1: bucket histogram (LDS-privatized) ----------------
__global__ __launch_bounds__(256) void bucket_hist(const int* __restrict__ dst,
                                                   int* __restrict__ bhist, int nE) {
    __shared__ int h[MAXB];
    for (int i = threadIdx.x; i < MAXB; i += 256) h[i] = 0;
    __syncthreads();
    int e0 = blockIdx.x * 8192;
    int cnt = min(8192, nE - e0);
    for (int i = threadIdx.x; i < cnt; i += 256)
        atomicAdd(&h[(unsigned)dst[e0 + i] >> BK_LOG], 1);
    __syncthreads();
    for (int i = threadIdx.x; i < MAXB; i += 256)
        if (h[i]) atomicAdd(&bhist[i], h[i]);
}

// ---------------- stage 2: scan bucket counts (1 block) ----------------
__global__ __launch_bounds__(256) void bucket_scan(const int* __restrict__ bhist,
                                                   int* __restrict__ bbase,
                                                   int* __restrict__ cursor,
                                                   int nb, int nE) {
    __shared__ int s4[256];
    int t = threadIdx.x;
    int v[4]; int sum = 0;
#pragma unroll
    for (int j = 0; j < 4; ++j) {
        int b = 4 * t + j;
        v[j] = (b < nb) ? bhist[b] : 0;
        sum += v[j];
    }
    s4[t] = sum;
    __syncthreads();
    for (int off = 1; off < 256; off <<= 1) {
        int mine = s4[t];
        int add = (t >= off) ? s4[t - off] : 0;
        __syncthreads();
        s4[t] = mine + add;
        __syncthreads();
    }
    int run = s4[t] - sum;
#pragma unroll
    for (int j = 0; j < 4; ++j) {
        int b = 4 * t + j;
        if (b < nb) { bbase[b] = run; cursor[b] = run; }
        run += v[j];
    }
    if (t == 0) bbase[nb] = nE;
}

// ---------------- stage 3: partition edges into buckets (coalesced) --------
__global__ __launch_bounds__(256) void partition_kernel(
        const int* __restrict__ src, const int* __restrict__ dst,
        int* __restrict__ cursor, unsigned int* __restrict__ ebuf, int nE) {
    __shared__ int lh[MAXB];
    __shared__ int lrun[MAXB];
    __shared__ int lcur[MAXB];
    __shared__ int swp[256];
    __shared__ unsigned int stg[EPB1];
    __shared__ unsigned short sbk[EPB1];
    int t = threadIdx.x;
    int e0 = blockIdx.x * EPB1;
    int cnt = min(EPB1, nE - e0);
    for (int i = t; i < MAXB; i += 256) lh[i] = 0;
    __syncthreads();
    for (int i = t; i < cnt; i += 256)
        atomicAdd(&lh[(unsigned)dst[e0 + i] >> BK_LOG], 1);
    __syncthreads();
    int v[4]; int sum = 0;
#pragma unroll
    for (int j = 0; j < 4; ++j) { v[j] = lh[4 * t + j]; sum += v[j]; }
    swp[t] = sum;
    __syncthreads();
    for (int off = 1; off < 256; off <<= 1) {
        int mine = swp[t];
        int add = (t >= off) ? swp[t - off] : 0;
        __syncthreads();
        swp[t] = mine + add;
        __syncthreads();
    }
    int run = swp[t] - sum;
#pragma unroll
    for (int j = 0; j < 4; ++j) {
        int b = 4 * t + j;
        lh[b] = run;
        lcur[b] = 0;
        if (v[j] > 0) lrun[b] = atomicAdd(&cursor[b], v[j]);
        run += v[j];
    }
    __syncthreads();
    for (int i = t; i < cnt; i += 256) {
        int d = dst[e0 + i];
        int s = src[e0 + i];
        int b = (unsigned)d >> BK_LOG;
        int lp = atomicAdd(&lcur[b], 1);
        int slot = lh[b] + lp;
        stg[slot] = ((unsigned)(d & (BK_NODES - 1)) << 17) | (unsigned)s;
        sbk[slot] = (unsigned short)b;
    }
    __syncthreads();
    for (int i = t; i < cnt; i += 256) {
        int b = sbk[i];
        int g = lrun[b] + (i - lh[b]);
        ebuf[g] = stg[i];
    }
}

// ---- stage 4: per-bucket sort by (src-range, dst_local) + gp tables -------
// gp64[b*65 + r*8 + g]  = start of (block b, range r, 16-node chunk g);
// gp64[b*65 + 64] = end. gp32: 16 chunks of 8 nodes, stride 129.
// dinv from per-node degree. Edge words keep full (dst_local<<17)|src.
__global__ __launch_bounds__(256) void bucket_csr_kernel(
        unsigned int* __restrict__ ebuf, const int* __restrict__ bbase,
        float* __restrict__ dinv, int* __restrict__ gp64, int* __restrict__ gp32,
        int nN) {
    int b = blockIdx.x;
    int node_lo = b << BK_LOG;
    int nn = min(BK_NODES, nN - node_lo);
    int base = bbase[b];
    int cnt = bbase[b + 1] - base;
    if (cnt > BCAP) cnt = BCAP;
    __shared__ unsigned int in[BCAP];
    __shared__ unsigned int outb[BCAP];
    __shared__ int h[NKEY], sc[NKEY], lc[NKEY];
    __shared__ int swp[256];
    int t = threadIdx.x;
    for (int i = t; i < cnt; i += 256) in[i] = ebuf[base + i];
    for (int i = t; i < NKEY; i += 256) { h[i] = 0; lc[i] = 0; }
    __syncthreads();
    for (int i = t; i < cnt; i += 256) {
        unsigned int w = in[i];
        int kk = (int)(((w & 0x1FFFFu) >> RNG_LOG) << BK_LOG) | (int)(w >> 17);
        atomicAdd(&h[kk], 1);
    }
    __syncthreads();
    int v[4]; int sum = 0;
#pragma unroll
    for (int j = 0; j < 4; ++j) { v[j] = h[4 * t + j]; sum += v[j]; }
    swp[t] = sum;
    __syncthreads();
    for (int off = 1; off < 256; off <<= 1) {
        int mine = swp[t];
        int add = (t >= off) ? swp[t - off] : 0;
        __syncthreads();
        swp[t] = mine + add;
        __syncthreads();
    }
    int run = swp[t] - sum;
#pragma unroll
    for (int j = 0; j < 4; ++j) { sc[4 * t + j] = run; run += v[j]; }
    __syncthreads();
    // chunk pointer tables (flat index t = r*G + g)
    if (t < 64)  gp64[b * 65 + t]  = base + sc[((t >> 3) << BK_LOG) | ((t & 7)  << 4)];
    if (t < 128) gp32[b * 129 + t] = base + sc[((t >> 4) << BK_LOG) | ((t & 15) << 3)];
    if (t == 0) { gp64[b * 65 + 64] = base + cnt; gp32[b * 129 + 128] = base + cnt; }
    // per-node degree -> dinv
    if (t < nn) {
        int deg = 0;
#pragma unroll
        for (int r = 0; r < NR; ++r) deg += h[(r << BK_LOG) | t];
        dinv[node_lo + t] = rsqrtf((float)deg + 1.0f);
    }
    __syncthreads();
    for (int i = t; i < cnt; i += 256) {
        unsigned int w = in[i];
        int kk = (int)(((w & 0x1FFFFu) >> RNG_LOG) << BK_LOG) | (int)(w >> 17);
        int lp = atomicAdd(&lc[kk], 1);
        outb[sc[kk] + lp] = w;   // keep full payload
    }
    __syncthreads();
    for (int i = t; i < cnt; i += 256) ebuf[base + i] = outb[i];
}

// ---------------- pad + pre-scale helpers ----------------
// xp[node][c] = half( x[node][c] * dinv[node] )  (pre-scaled gather operand)
__global__ void padx_kernel(const float* __restrict__ x, const float* __restrict__ dinv,
                            __half* __restrict__ xp, int n) {
    int i = blockIdx.x * 256 + threadIdx.x;   // one thread per 2 cols
    if (i < n * 16) {
        int node = i >> 4, c2 = (i & 15) * 2;
        float s = dinv[node];
        float v0 = (c2     < IN_DIM) ? x[(size_t)node * IN_DIM + c2    ] * s : 0.f;
        float v1 = (c2 + 1 < IN_DIM) ? x[(size_t)node * IN_DIM + c2 + 1] * s : 0.f;
        *(__half2*)&xp[(size_t)node * 32 + c2] = __floats2half2_rn(v0, v1);
    }
}

__global__ void padw_kernel(const float* __restrict__ W1, float* __restrict__ W1p) {
    int i = blockIdx.x * 256 + threadIdx.x;
    if (i < 32 * HID) {
        int r = i >> 6, c = i & 63;
        W1p[i] = (r < IN_DIM) ? W1[r * HID + c] : 0.f;
    }
}

// ---------------- dense layer: out = in @ W [*dinv->half] [+bias,relu] -----
// SCALE=true writes __half (gather operand); SCALE=false writes float.
template<int INF, int OUTF, bool ACT, bool SCALE>
__global__ __launch_bounds__(256) void gemm_kernel(
        const float* __restrict__ in, const float* __restrict__ W,
        const float* __restrict__ bias, const float* __restrict__ dinv,
        void* __restrict__ out, int n) {
    constexpr int TPN = OUTF / 4;
    constexpr int NPB = 256 / TPN;
    constexpr int LDK = INF + 4;
    __shared__ float sW[INF * OUTF];
    __shared__ float sIn[NPB][LDK];
    for (int i = threadIdx.x; i < INF * OUTF; i += 256) sW[i] = W[i];
    int node0 = blockIdx.x * NPB;
    for (int i = threadIdx.x; i < NPB * INF; i += 256) {
        int ln = i / INF, k = i % INF;
        int node = node0 + ln;
        sIn[ln][k] = (node < n) ? in[(size_t)node * INF + k] : 0.f;
    }
    __syncthreads();
    int g   = threadIdx.x / TPN;
    int of0 = (threadIdx.x % TPN) * 4;
    int node = node0 + g;
    float4 acc = make_float4(0.f, 0.f, 0.f, 0.f);
#pragma unroll
    for (int k = 0; k < INF; ++k) {
        float aj = sIn[g][k];
        const float4 wv = *(const float4*)&sW[k * OUTF + of0];
        acc.x += aj * wv.x; acc.y += aj * wv.y;
        acc.z += aj * wv.z; acc.w += aj * wv.w;
    }
    if (ACT) {
        const float4 bv = *(const float4*)&bias[of0];
        acc.x = fmaxf(acc.x + bv.x, 0.f);
        acc.y = fmaxf(acc.y + bv.y, 0.f);
        acc.z = fmaxf(acc.z + bv.z, 0.f);
        acc.w = fmaxf(acc.w + bv.w, 0.f);
    }
    if (node < n) {
        if (SCALE) {
            float s = dinv[node];
            union { __half2 h[2]; uint2 u; } pk;
            pk.h[0] = __floats2half2_rn(acc.x * s, acc.y * s);
            pk.h[1] = __floats2half2_rn(acc.z * s, acc.w * s);
            *(uint2*)((__half*)out + (size_t)node * OUTF + of0) = pk.u;
        } else {
            *(float4*)((float*)out + (size_t)node * OUTF + of0) = acc;
        }
    }
}

// ---- phased streaming gather: register accumulate, LDS flush on boundary --
// out[d] = act( dinv[d] * (hp[d] + sum_cols hp[c]) + bias )
// Group of F/2 lanes owns K=128/G nodes; its (range, chunk) edges are one
// contiguous dst-sorted run. Flat unroll-8 sweep; flush register acc to the
// group's exclusive LDS row when dst changes (~every 4 edges). Dummy row 128
// absorbs +0 flushes (racy but value-preserving). Barrier per range.
template<int F, bool ACT>
__global__ __launch_bounds__(256) void gatherp_kernel(
        const __half* __restrict__ hp, const float* __restrict__ dinv,
        const int* __restrict__ gp, const unsigned int* __restrict__ eb,
        const float* __restrict__ bias, float* __restrict__ agg, int n) {
    constexpr int LPN = F / 2;          // lanes per group (half2 each)
    constexpr int G   = 256 / LPN;      // groups per block (8 or 16)
    constexpr int GPB = NR * G + 1;     // gp stride per bucket (65 or 129)
    __shared__ float acc[(BK_NODES + 1) * F];   // row 128 = dummy
    int b = blockIdx.x, t = threadIdx.x;
    int node_lo = b << BK_LOG;
    // self-loop init (pre-scaled rows); zero for OOB nodes
    for (int i = t; i < BK_NODES * LPN; i += 256) {
        int ln = i / LPN, c2 = (i % LPN) * 2;
        int node = node_lo + ln;
        float2 v = make_float2(0.f, 0.f);
        if (node < n)
            v = __half22float2(*(const __half2*)&hp[(size_t)node * F + c2]);
        acc[ln * F + c2] = v.x;
        acc[ln * F + c2 + 1] = v.y;
    }
    __syncthreads();
    int g  = t / LPN;
    int c2 = (t % LPN) * 2;
    float ax = 0.f, ay = 0.f;
    int cur = BK_NODES;                 // dummy row
    for (int r = 0; r < NR; ++r) {
        int e  = gp[b * GPB + r * G + g];
        int e1 = gp[b * GPB + r * G + g + 1];
        for (; e + 8 <= e1; e += 8) {
            unsigned int w[8];
#pragma unroll
            for (int u = 0; u < 8; ++u) w[u] = eb[e + u];
            float2 v[8];
#pragma unroll
            for (int u = 0; u < 8; ++u)
                v[u] = __half22float2(
                    *(const __half2*)&hp[(size_t)(w[u] & 0x1FFFFu) * F + c2]);
#pragma unroll
            for (int u = 0; u < 8; ++u) {
                int dl = (int)(w[u] >> 17);
                if (dl != cur) {
                    acc[cur * F + c2]     += ax;
                    acc[cur * F + c2 + 1] += ay;
                    ax = 0.f; ay = 0.f; cur = dl;
                }
                ax += v[u].x; ay += v[u].y;
            }
        }
        for (; e < e1; ++e) {
            unsigned int w = eb[e];
            float2 v = __half22float2(
                *(const __half2*)&hp[(size_t)(w & 0x1FFFFu) * F + c2]);
            int dl = (int)(w >> 17);
            if (dl != cur) {
                acc[cur * F + c2]     += ax;
                acc[cur * F + c2 + 1] += ay;
                ax = 0.f; ay = 0.f; cur = dl;
            }
            ax += v.x; ay += v.y;
        }
        // range-end flush + reset, then phase barrier
        acc[cur * F + c2]     += ax;
        acc[cur * F + c2 + 1] += ay;
        ax = 0.f; ay = 0.f; cur = BK_NODES;
        __syncthreads();
    }
    // epilogue: scale, bias, relu, NT store
    for (int i = t; i < BK_NODES * LPN; i += 256) {
        int ln = i / LPN, cc = (i % LPN) * 2;
        int node = node_lo + ln;
        if (node < n) {
            float s = dinv[node];
            float rx = acc[ln * F + cc] * s;
            float ry = acc[ln * F + cc + 1] * s;
            if (ACT) {
                rx = fmaxf(rx + bias[cc], 0.f);
                ry = fmaxf(ry + bias[cc + 1], 0.f);
            }
            union { float2 f; unsigned long long u; } o;
            o.f = make_float2(rx, ry);
            __builtin_nontemporal_store(o.u,
                (unsigned long long*)&agg[(size_t)node * F + cc]);
        }
    }
}

// ---------------- mean pool ----------------
__global__ __launch_bounds__(256) void pool_kernel(
        const float* __restrict__ h3, const int* __restrict__ batch,
        int n, float* __restrict__ pool) {
    int g = blockIdx.x;
    int lo = 0, hi = n;
    while (lo < hi) { int m = (lo + hi) >> 1; if (batch[m] < g) lo = m + 1; else hi = m; }
    int s = lo;
    hi = n;
    while (lo < hi) { int m = (lo + hi) >> 1; if (batch[m] < g + 1) lo = m + 1; else hi = m; }
    int e = lo;
    constexpr int F = OUT3;
    int ln = threadIdx.x / F;
    int f  = threadIdx.x % F;
    float acc = 0.f;
    for (int i = s + ln; i < e; i += 8)
        acc += h3[(size_t)i * F + f];
    __shared__ float red[8][F];
    red[ln][f] = acc;
    __syncthreads();
    if (ln == 0) {
        float t = 0.f;
#pragma unroll
        for (int j = 0; j < 8; ++j) t += red[j][f];
        float cnt = (float)((e - s) > 0 ? (e - s) : 1);
        pool[g * F + f] = t / cnt;
    }
}

// ---------------- head ----------------
__global__ __launch_bounds__(256) void head_kernel(
        const float* __restrict__ pool, const float* __restrict__ Wh1,
        const float* __restrict__ bh1, const float* __restrict__ Wh2,
        const float* __restrict__ bh2, float* __restrict__ out) {
    __shared__ float sW1[32 * 32];
    __shared__ float sb1[32];
    __shared__ float sW2[32];
    int t = threadIdx.x;
    for (int i = t; i < 1024; i += 256) sW1[i] = Wh1[i];
    if (t < 32) { sb1[t] = bh1[t]; sW2[t] = Wh2[t]; }
    __syncthreads();
    int g = t;
    float y = bh2[0];
    const float* p = &pool[g * 32];
#pragma unroll 4
    for (int j = 0; j < 32; ++j) {
        float a = sb1[j];
#pragma unroll
        for (int k = 0; k < 32; ++k) a += p[k] * sW1[k * 32 + j];
        y += fmaxf(a, 0.f) * sW2[j];
    }
    out[g] = y;
}

extern "C" void kernel_launch(void* const* d_in, const int* in_sizes, int n_in,
                              void* d_out, int out_size, void* d_ws, size_t ws_size,
                              hipStream_t stream) {
    const float* x    = (const float*)d_in[0];
    const int*   ei   = (const int*)  d_in[1];
    const int*   batch= (const int*)  d_in[2];
    const float* W1   = (const float*)d_in[3];
    const float* b1   = (const float*)d_in[4];
    const float* W2   = (const float*)d_in[5];
    const float* b2   = (const float*)d_in[6];
    const float* W3   = (const float*)d_in[7];
    const float* b3   = (const float*)d_in[8];
    const float* Wh1  = (const float*)d_in[9];
    const float* bh1  = (const float*)d_in[10];
    const float* Wh2  = (const float*)d_in[11];
    const float* bh2  = (const float*)d_in[12];
    float* out = (float*)d_out;

    const int N = in_sizes[0] / IN_DIM;
    const int E = in_sizes[1] / 2;
    const int* src = ei;
    const int* dst = ei + E;
    const int NB = (N + BK_NODES - 1) >> BK_LOG;

    // workspace layout (all 4B elements; half buffers alias the fp32 ones)
    char* base = (char*)d_ws;
    unsigned int* ebuf = (unsigned int*)base;       base += (size_t)E * 4;
    int*   bhist   = (int*)base;                    base += (size_t)MAXB * 4;
    int*   bbase   = (int*)base;                    base += (size_t)(MAXB + 1) * 4;
    int*   cursor  = (int*)base;                    base += (size_t)MAXB * 4;
    int*   gp64    = (int*)base;                    base += (size_t)MAXB * 65 * 4;
    int*   gp32    = (int*)base;                    base += (size_t)MAXB * 129 * 4;
    float* dinv    = (float*)base;                  base += (size_t)N * 4;
    float* W1p     = (float*)base;                  base += (size_t)32 * HID * 4;
    float* bufA    = (float*)base;                  base += (size_t)N * HID * 4;
    float* bufB    = (float*)base;                  base += (size_t)N * HID * 4;
    float* pool    = (float*)base;

    // ---- CSR build (counting sort; buckets ordered by (range, dst_local)) --
    hipMemsetAsync(bhist, 0, (size_t)MAXB * sizeof(int), stream);
    bucket_hist<<<(E + 8191) / 8192, 256, 0, stream>>>(dst, bhist, E);
    bucket_scan<<<1, 256, 0, stream>>>(bhist, bbase, cursor, NB, E);
    partition_kernel<<<(E + EPB1 - 1) / EPB1, 256, 0, stream>>>(src, dst, cursor, ebuf, E);
    bucket_csr_kernel<<<NB, 256, 0, stream>>>(ebuf, bbase, dinv, gp64, gp32, N);

    // ---- layer 1 (reordered): aggX = A_hat Xp' ; h1 = relu(aggX @ W1p + b1)
    // xp (half) in bufB; aggX (fp32) in bufA; h1 (fp32) back in bufB.
    padx_kernel<<<((size_t)N * 16 + 255) / 256, 256, 0, stream>>>(x, dinv, (__half*)bufB, N);
    padw_kernel<<<(32 * HID + 255) / 256, 256, 0, stream>>>(W1, W1p);
    gatherp_kernel<32, false><<<NB, 256, 0, stream>>>((const __half*)bufB, dinv, gp32, ebuf, nullptr, bufA, N);
    gemm_kernel<32, HID, true, false><<<(N + 15) / 16, 256, 0, stream>>>(bufA, W1p, b1, nullptr, bufB, N);

    // ---- layer 2: t2' = half((h1 @ W2)*dinv) ; h2 = relu(dinv*(sum t2') + b2)
    gemm_kernel<HID, HID, false, true><<<(N + 15) / 16, 256, 0, stream>>>(bufB, W2, nullptr, dinv, bufA, N);
    gatherp_kernel<64, true><<<NB, 256, 0, stream>>>((const __half*)bufA, dinv, gp64, ebuf, b2, bufB, N);

    // ---- layer 3: t3' = half((h2 @ W3)*dinv) ; h3 = relu(dinv*(sum t3') + b3)
    gemm_kernel<HID, OUT3, false, true><<<(N + 31) / 32, 256, 0, stream>>>(bufB, W3, nullptr, dinv, bufA, N);
    gatherp_kernel<32, true><<<NB, 256, 0, stream>>>((const __half*)bufA, dinv, gp32, ebuf, b3, bufB, N);

    // ---- pool + head ----
    pool_kernel<<<256, 256, 0, stream>>>(bufB, batch, N, pool);
    head_kernel<<<1, 256, 0, stream>>>(pool, Wh1, bh1, Wh2, bh2, out);
}

// Round 7
// 473.969 us; speedup vs baseline: 6.2828x; 1.0930x over previous
//
#include <hip/hip_runtime.h>
#include <hip/hip_fp16.h>

// GNN: 3x GCNConv (25->64->64->32) + global mean pool (256 graphs) + MLP head.
// Round 12: R11 structure with 64-node buckets for occupancy.
// R11 proved the phased streaming gather (register acc + boundary LDS flush):
// FETCH 315->63MB, 0 bank conflicts. But dur stuck at 103us: VALUBusy 33%,
// Occupancy 29% -- grid was 782 blocks = 3.05/CU resident (LDS 33KB, phasing
// pins grid = bucket count). R12: BK_NODES 128->64 -> 1563 blocks = 6.1/CU,
// LDS 16.6KB (F=64) / 8.3KB (F=32), launch_bounds(256,6). Groups own 8 nodes
// (F=64) -> ~32-edge dst-sorted runs per range, still unroll-8 streamable.
// Sort/flush/phasing/fp16 payload unchanged (single-variable experiment).
// Assumes N < 2^17 for the 17-bit src packing.

#define IN_DIM 25
#define HID 64
#define OUT3 32
#define BK_LOG 6
#define BK_NODES 64
#define MAXB 2048
#define NPT 8           // MAXB / 256
#define EPB1 16384
#define BCAP 4096
#define RNG_LOG 14      // src-range = src >> 14  (8 ranges cover N < 131072)
#define NR 8
#define NKEY (BK_NODES * NR)   // 512

// ---------------- stage 1: bucket histogram (LDS-privatized) ----------------
__global__ __launch_bounds__(256) void bucket_hist(const int* __restrict__ dst,
                                                   int* __restrict__ bhist, int nE) {
    __shared__ int h[MAXB];
    for (int i = threadIdx.x; i < MAXB; i += 256) h[i] = 0;
    __syncthreads();
    int e0 = blockIdx.x * 8192;
    int cnt = min(8192, nE - e0);
    for (int i = threadIdx.x; i < cnt; i += 256)
        atomicAdd(&h[(unsigned)dst[e0 + i] >> BK_LOG], 1);
    __syncthreads();
    for (int i = threadIdx.x; i < MAXB; i += 256)
        if (h[i]) atomicAdd(&bhist[i], h[i]);
}

// ---------------- stage 2: scan bucket counts (1 block) ----------------
__global__ __launch_bounds__(256) void bucket_scan(const int* __restrict__ bhist,
                                                   int* __restrict__ bbase,
                                                   int* __restrict__ cursor,
                                                   int nb, int nE) {
    __shared__ int s4[256];
    int t = threadIdx.x;
    int v[NPT]; int sum = 0;
#pragma unroll
    for (int j = 0; j < NPT; ++j) {
        int b = NPT * t + j;
        v[j] = (b < nb) ? bhist[b] : 0;
        sum += v[j];
    }
    s4[t] = sum;
    __syncthreads();
    for (int off = 1; off < 256; off <<= 1) {
        int mine = s4[t];
        int add = (t >= off) ? s4[t - off] : 0;
        __syncthreads();
        s4[t] = mine + add;
        __syncthreads();
    }
    int run = s4[t] - sum;
#pragma unroll
    for (int j = 0; j < NPT; ++j) {
        int b = NPT * t + j;
        if (b < nb) { bbase[b] = run; cursor[b] = run; }
        run += v[j];
    }
    if (t == 0) bbase[nb] = nE;
}

// ---------------- stage 3: partition edges into buckets (coalesced) --------
__global__ __launch_bounds__(256) void partition_kernel(
        const int* __restrict__ src, const int* __restrict__ dst,
        int* __restrict__ cursor, unsigned int* __restrict__ ebuf, int nE) {
    __shared__ int lh[MAXB];
    __shared__ int lrun[MAXB];
    __shared__ int lcur[MAXB];
    __shared__ int swp[256];
    __shared__ unsigned int stg[EPB1];
    __shared__ unsigned short sbk[EPB1];
    int t = threadIdx.x;
    int e0 = blockIdx.x * EPB1;
    int cnt = min(EPB1, nE - e0);
    for (int i = t; i < MAXB; i += 256) lh[i] = 0;
    __syncthreads();
    for (int i = t; i < cnt; i += 256)
        atomicAdd(&lh[(unsigned)dst[e0 + i] >> BK_LOG], 1);
    __syncthreads();
    int v[NPT]; int sum = 0;
#pragma unroll
    for (int j = 0; j < NPT; ++j) { v[j] = lh[NPT * t + j]; sum += v[j]; }
    swp[t] = sum;
    __syncthreads();
    for (int off = 1; off < 256; off <<= 1) {
        int mine = swp[t];
        int add = (t >= off) ? swp[t - off] : 0;
        __syncthreads();
        swp[t] = mine + add;
        __syncthreads();
    }
    int run = swp[t] - sum;
#pragma unroll
    for (int j = 0; j < NPT; ++j) {
        int b = NPT * t + j;
        lh[b] = run;
        lcur[b] = 0;
        if (v[j] > 0) lrun[b] = atomicAdd(&cursor[b], v[j]);
        run += v[j];
    }
    __syncthreads();
    for (int i = t; i < cnt; i += 256) {
        int d = dst[e0 + i];
        int s = src[e0 + i];
        int b = (unsigned)d >> BK_LOG;
        int lp = atomicAdd(&lcur[b], 1);
        int slot = lh[b] + lp;
        stg[slot] = ((unsigned)(d & (BK_NODES - 1)) << 17) | (unsigned)s;
        sbk[slot] = (unsigned short)b;
    }
    __syncthreads();
    for (int i = t; i < cnt; i += 256) {
        int b = sbk[i];
        int g = lrun[b] + (i - lh[b]);
        ebuf[g] = stg[i];
    }
}

// ---- stage 4: per-bucket sort by (src-range, dst_local) + gp tables -------
// gp64[b*65 + r*8 + g]  = start of (block b, range r, 8-node chunk g);
// gp64[b*65+64] = end. gp32[b*129 + r*16 + g]: 16 chunks of 4 nodes.
// dinv from per-node degree. Edge words keep full (dst_local<<17)|src.
__global__ __launch_bounds__(256) void bucket_csr_kernel(
        unsigned int* __restrict__ ebuf, const int* __restrict__ bbase,
        float* __restrict__ dinv, int* __restrict__ gp64, int* __restrict__ gp32,
        int nN) {
    int b = blockIdx.x;
    int node_lo = b << BK_LOG;
    int nn = min(BK_NODES, nN - node_lo);
    int base = bbase[b];
    int cnt = bbase[b + 1] - base;
    if (cnt > BCAP) cnt = BCAP;
    __shared__ unsigned int in[BCAP];
    __shared__ unsigned int outb[BCAP];
    __shared__ int h[NKEY], sc[NKEY], lc[NKEY];
    __shared__ int swp[256];
    int t = threadIdx.x;
    for (int i = t; i < cnt; i += 256) in[i] = ebuf[base + i];
    for (int i = t; i < NKEY; i += 256) { h[i] = 0; lc[i] = 0; }
    __syncthreads();
    for (int i = t; i < cnt; i += 256) {
        unsigned int w = in[i];
        int kk = (int)(((w & 0x1FFFFu) >> RNG_LOG) << BK_LOG) | (int)(w >> 17);
        atomicAdd(&h[kk], 1);
    }
    __syncthreads();
    int v[2]; int sum = 0;
#pragma unroll
    for (int j = 0; j < 2; ++j) { v[j] = h[2 * t + j]; sum += v[j]; }
    swp[t] = sum;
    __syncthreads();
    for (int off = 1; off < 256; off <<= 1) {
        int mine = swp[t];
        int add = (t >= off) ? swp[t - off] : 0;
        __syncthreads();
        swp[t] = mine + add;
        __syncthreads();
    }
    int run = swp[t] - sum;
#pragma unroll
    for (int j = 0; j < 2; ++j) { sc[2 * t + j] = run; run += v[j]; }
    __syncthreads();
    // chunk pointer tables (flat index t = r*G + g)
    if (t < 64)  gp64[b * 65 + t]  = base + sc[((t >> 3) << BK_LOG) | ((t & 7)  << 3)];
    if (t < 128) gp32[b * 129 + t] = base + sc[((t >> 4) << BK_LOG) | ((t & 15) << 2)];
    if (t == 0) { gp64[b * 65 + 64] = base + cnt; gp32[b * 129 + 128] = base + cnt; }
    // per-node degree -> dinv
    if (t < nn) {
        int deg = 0;
#pragma unroll
        for (int r = 0; r < NR; ++r) deg += h[(r << BK_LOG) | t];
        dinv[node_lo + t] = rsqrtf((float)deg + 1.0f);
    }
    __syncthreads();
    for (int i = t; i < cnt; i += 256) {
        unsigned int w = in[i];
        int kk = (int)(((w & 0x1FFFFu) >> RNG_LOG) << BK_LOG) | (int)(w >> 17);
        int lp = atomicAdd(&lc[kk], 1);
        outb[sc[kk] + lp] = w;   // keep full payload
    }
    __syncthreads();
    for (int i = t; i < cnt; i += 256) ebuf[base + i] = outb[i];
}

// ---------------- pad + pre-scale helpers ----------------
// xp[node][c] = half( x[node][c] * dinv[node] )  (pre-scaled gather operand)
__global__ void padx_kernel(const float* __restrict__ x, const float* __restrict__ dinv,
                            __half* __restrict__ xp, int n) {
    int i = blockIdx.x * 256 + threadIdx.x;   // one thread per 2 cols
    if (i < n * 16) {
        int node = i >> 4, c2 = (i & 15) * 2;
        float s = dinv[node];
        float v0 = (c2     < IN_DIM) ? x[(size_t)node * IN_DIM + c2    ] * s : 0.f;
        float v1 = (c2 + 1 < IN_DIM) ? x[(size_t)node * IN_DIM + c2 + 1] * s : 0.f;
        *(__half2*)&xp[(size_t)node * 32 + c2] = __floats2half2_rn(v0, v1);
    }
}

__global__ void padw_kernel(const float* __restrict__ W1, float* __restrict__ W1p) {
    int i = blockIdx.x * 256 + threadIdx.x;
    if (i < 32 * HID) {
        int r = i >> 6, c = i & 63;
        W1p[i] = (r < IN_DIM) ? W1[r * HID + c] : 0.f;
    }
}

// ---------------- dense layer: out = in @ W [*dinv->half] [+bias,relu] -----
// SCALE=true writes __half (gather operand); SCALE=false writes float.
template<int INF, int OUTF, bool ACT, bool SCALE>
__global__ __launch_bounds__(256) void gemm_kernel(
        const float* __restrict__ in, const float* __restrict__ W,
        const float* __restrict__ bias, const float* __restrict__ dinv,
        void* __restrict__ out, int n) {
    constexpr int TPN = OUTF / 4;
    constexpr int NPB = 256 / TPN;
    constexpr int LDK = INF + 4;
    __shared__ float sW[INF * OUTF];
    __shared__ float sIn[NPB][LDK];
    for (int i = threadIdx.x; i < INF * OUTF; i += 256) sW[i] = W[i];
    int node0 = blockIdx.x * NPB;
    for (int i = threadIdx.x; i < NPB * INF; i += 256) {
        int ln = i / INF, k = i % INF;
        int node = node0 + ln;
        sIn[ln][k] = (node < n) ? in[(size_t)node * INF + k] : 0.f;
    }
    __syncthreads();
    int g   = threadIdx.x / TPN;
    int of0 = (threadIdx.x % TPN) * 4;
    int node = node0 + g;
    float4 acc = make_float4(0.f, 0.f, 0.f, 0.f);
#pragma unroll
    for (int k = 0; k < INF; ++k) {
        float aj = sIn[g][k];
        const float4 wv = *(const float4*)&sW[k * OUTF + of0];
        acc.x += aj * wv.x; acc.y += aj * wv.y;
        acc.z += aj * wv.z; acc.w += aj * wv.w;
    }
    if (ACT) {
        const float4 bv = *(const float4*)&bias[of0];
        acc.x = fmaxf(acc.x + bv.x, 0.f);
        acc.y = fmaxf(acc.y + bv.y, 0.f);
        acc.z = fmaxf(acc.z + bv.z, 0.f);
        acc.w = fmaxf(acc.w + bv.w, 0.f);
    }
    if (node < n) {
        if (SCALE) {
            float s = dinv[node];
            union { __half2 h[2]; uint2 u; } pk;
            pk.h[0] = __floats2half2_rn(acc.x * s, acc.y * s);
            pk.h[1] = __floats2half2_rn(acc.z * s, acc.w * s);
            *(uint2*)((__half*)out + (size_t)node * OUTF + of0) = pk.u;
        } else {
            *(float4*)((float*)out + (size_t)node * OUTF + of0) = acc;
        }
    }
}

// ---- phased streaming gather: register accumulate, LDS flush on boundary --
// out[d] = act( dinv[d] * (hp[d] + sum_cols hp[c]) + bias )
// Group of F/2 lanes owns 64/G nodes; its (range, chunk) edges are one
// contiguous dst-sorted run. Flat unroll-8 sweep; flush register acc to the
// group's exclusive LDS rows when dst changes. Dummy row 64 absorbs +0
// flushes (racy but value-preserving). Barrier per range keeps the resident
// grid phased.
template<int F, bool ACT>
__global__ __launch_bounds__(256, 6) void gatherp_kernel(
        const __half* __restrict__ hp, const float* __restrict__ dinv,
        const int* __restrict__ gp, const unsigned int* __restrict__ eb,
        const float* __restrict__ bias, float* __restrict__ agg, int n) {
    constexpr int LPN = F / 2;          // lanes per group (half2 each)
    constexpr int G   = 256 / LPN;      // groups per block (8 or 16)
    constexpr int GPB = NR * G + 1;     // gp stride per bucket (65 or 129)
    __shared__ float acc[(BK_NODES + 1) * F];   // row 64 = dummy
    int b = blockIdx.x, t = threadIdx.x;
    int node_lo = b << BK_LOG;
    // self-loop init (pre-scaled rows); zero for OOB nodes
    for (int i = t; i < BK_NODES * LPN; i += 256) {
        int ln = i / LPN, c2 = (i % LPN) * 2;
        int node = node_lo + ln;
        float2 v = make_float2(0.f, 0.f);
        if (node < n)
            v = __half22float2(*(const __half2*)&hp[(size_t)node * F + c2]);
        acc[ln * F + c2] = v.x;
        acc[ln * F + c2 + 1] = v.y;
    }
    __syncthreads();
    int g  = t / LPN;
    int c2 = (t % LPN) * 2;
    float ax = 0.f, ay = 0.f;
    int cur = BK_NODES;                 // dummy row
    for (int r = 0; r < NR; ++r) {
        int e  = gp[b * GPB + r * G + g];
        int e1 = gp[b * GPB + r * G + g + 1];
        for (; e + 8 <= e1; e += 8) {
            unsigned int w[8];
#pragma unroll
            for (int u = 0; u < 8; ++u) w[u] = eb[e + u];
            float2 v[8];
#pragma unroll
            for (int u = 0; u < 8; ++u)
                v[u] = __half22float2(
                    *(const __half2*)&hp[(size_t)(w[u] & 0x1FFFFu) * F + c2]);
#pragma unroll
            for (int u = 0; u < 8; ++u) {
                int dl = (int)(w[u] >> 17);
                if (dl != cur) {
                    acc[cur * F + c2]     += ax;
                    acc[cur * F + c2 + 1] += ay;
                    ax = 0.f; ay = 0.f; cur = dl;
                }
                ax += v[u].x; ay += v[u].y;
            }
        }
        for (; e < e1; ++e) {
            unsigned int w = eb[e];
            float2 v = __half22float2(
                *(const __half2*)&hp[(size_t)(w & 0x1FFFFu) * F + c2]);
            int dl = (int)(w >> 17);
            if (dl != cur) {
                acc[cur * F + c2]     += ax;
                acc[cur * F + c2 + 1] += ay;
                ax = 0.f; ay = 0.f; cur = dl;
            }
            ax += v.x; ay += v.y;
        }
        // range-end flush + reset, then phase barrier
        acc[cur * F + c2]     += ax;
        acc[cur * F + c2 + 1] += ay;
        ax = 0.f; ay = 0.f; cur = BK_NODES;
        __syncthreads();
    }
    // epilogue: scale, bias, relu, NT store
    for (int i = t; i < BK_NODES * LPN; i += 256) {
        int ln = i / LPN, cc = (i % LPN) * 2;
        int node = node_lo + ln;
        if (node < n) {
            float s = dinv[node];
            float rx = acc[ln * F + cc] * s;
            float ry = acc[ln * F + cc + 1] * s;
            if (ACT) {
                rx = fmaxf(rx + bias[cc], 0.f);
                ry = fmaxf(ry + bias[cc + 1], 0.f);
            }
            union { float2 f; unsigned long long u; } o;
            o.f = make_float2(rx, ry);
            __builtin_nontemporal_store(o.u,
                (unsigned long long*)&agg[(size_t)node * F + cc]);
        }
    }
}

// ---------------- mean pool ----------------
__global__ __launch_bounds__(256) void pool_kernel(
        const float* __restrict__ h3, const int* __restrict__ batch,
        int n, float* __restrict__ pool) {
    int g = blockIdx.x;
    int lo = 0, hi = n;
    while (lo < hi) { int m = (lo + hi) >> 1; if (batch[m] < g) lo = m + 1; else hi = m; }
    int s = lo;
    hi = n;
    while (lo < hi) { int m = (lo + hi) >> 1; if (batch[m] < g + 1) lo = m + 1; else hi = m; }
    int e = lo;
    constexpr int F = OUT3;
    int ln = threadIdx.x / F;
    int f  = threadIdx.x % F;
    float acc = 0.f;
    for (int i = s + ln; i < e; i += 8)
        acc += h3[(size_t)i * F + f];
    __shared__ float red[8][F];
    red[ln][f] = acc;
    __syncthreads();
    if (ln == 0) {
        float t = 0.f;
#pragma unroll
        for (int j = 0; j < 8; ++j) t += red[j][f];
        float cnt = (float)((e - s) > 0 ? (e - s) : 1);
        pool[g * F + f] = t / cnt;
    }
}

// ---------------- head ----------------
__global__ __launch_bounds__(256) void head_kernel(
        const float* __restrict__ pool, const float* __restrict__ Wh1,
        const float* __restrict__ bh1, const float* __restrict__ Wh2,
        const float* __restrict__ bh2, float* __restrict__ out) {
    __shared__ float sW1[32 * 32];
    __shared__ float sb1[32];
    __shared__ float sW2[32];
    int t = threadIdx.x;
    for (int i = t; i < 1024; i += 256) sW1[i] = Wh1[i];
    if (t < 32) { sb1[t] = bh1[t]; sW2[t] = Wh2[t]; }
    __syncthreads();
    int g = t;
    float y = bh2[0];
    const float* p = &pool[g * 32];
#pragma unroll 4
    for (int j = 0; j < 32; ++j) {
        float a = sb1[j];
#pragma unroll
        for (int k = 0; k < 32; ++k) a += p[k] * sW1[k * 32 + j];
        y += fmaxf(a, 0.f) * sW2[j];
    }
    out[g] = y;
}

extern "C" void kernel_launch(void* const* d_in, const int* in_sizes, int n_in,
                              void* d_out, int out_size, void* d_ws, size_t ws_size,
                              hipStream_t stream) {
    const float* x    = (const float*)d_in[0];
    const int*   ei   = (const int*)  d_in[1];
    const int*   batch= (const int*)  d_in[2];
    const float* W1   = (const float*)d_in[3];
    const float* b1   = (const float*)d_in[4];
    const float* W2   = (const float*)d_in[5];
    const float* b2   = (const float*)d_in[6];
    const float* W3   = (const float*)d_in[7];
    const float* b3   = (const float*)d_in[8];
    const float* Wh1  = (const float*)d_in[9];
    const float* bh1  = (const float*)d_in[10];
    const float* Wh2  = (const float*)d_in[11];
    const float* bh2  = (const float*)d_in[12];
    float* out = (float*)d_out;

    const int N = in_sizes[0] / IN_DIM;
    const int E = in_sizes[1] / 2;
    const int* src = ei;
    const int* dst = ei + E;
    const int NB = (N + BK_NODES - 1) >> BK_LOG;

    // workspace layout (all 4B elements; half buffers alias the fp32 ones)
    char* base = (char*)d_ws;
    unsigned int* ebuf = (unsigned int*)base;       base += (size_t)E * 4;
    int*   bhist   = (int*)base;                    base += (size_t)MAXB * 4;
    int*   bbase   = (int*)base;                    base += (size_t)(MAXB + 1) * 4;
    int*   cursor  = (int*)base;                    base += (size_t)MAXB * 4;
    int*   gp64    = (int*)base;                    base += (size_t)MAXB * 65 * 4;
    int*   gp32    = (int*)base;                    base += (size_t)MAXB * 129 * 4;
    float* dinv    = (float*)base;                  base += (size_t)N * 4;
    float* W1p     = (float*)base;                  base += (size_t)32 * HID * 4;
    float* bufA    = (float*)base;                  base += (size_t)N * HID * 4;
    float* bufB    = (float*)base;                  base += (size_t)N * HID * 4;
    float* pool    = (float*)base;

    // ---- CSR build (counting sort; buckets ordered by (range, dst_local)) --
    hipMemsetAsync(bhist, 0, (size_t)MAXB * sizeof(int), stream);
    bucket_hist<<<(E + 8191) / 8192, 256, 0, stream>>>(dst, bhist, E);
    bucket_scan<<<1, 256, 0, stream>>>(bhist, bbase, cursor, NB, E);
    partition_kernel<<<(E + EPB1 - 1) / EPB1, 256, 0, stream>>>(src, dst, cursor, ebuf, E);
    bucket_csr_kernel<<<NB, 256, 0, stream>>>(ebuf, bbase, dinv, gp64, gp32, N);

    // ---- layer 1 (reordered): aggX = A_hat Xp' ; h1 = relu(aggX @ W1p + b1)
    // xp (half) in bufB; aggX (fp32) in bufA; h1 (fp32) back in bufB.
    padx_kernel<<<((size_t)N * 16 + 255) / 256, 256, 0, stream>>>(x, dinv, (__half*)bufB, N);
    padw_kernel<<<(32 * HID + 255) / 256, 256, 0, stream>>>(W1, W1p);
    gatherp_kernel<32, false><<<NB, 256, 0, stream>>>((const __half*)bufB, dinv, gp32, ebuf, nullptr, bufA, N);
    gemm_kernel<32, HID, true, false><<<(N + 15) / 16, 256, 0, stream>>>(bufA, W1p, b1, nullptr, bufB, N);

    // ---- layer 2: t2' = half((h1 @ W2)*dinv) ; h2 = relu(dinv*(sum t2') + b2)
    gemm_kernel<HID, HID, false, true><<<(N + 15) / 16, 256, 0, stream>>>(bufB, W2, nullptr, dinv, bufA, N);
    gatherp_kernel<64, true><<<NB, 256, 0, stream>>>((const __half*)bufA, dinv, gp64, ebuf, b2, bufB, N);

    // ---- layer 3: t3' = half((h2 @ W3)*dinv) ; h3 = relu(dinv*(sum t3') + b3)
    gemm_kernel<HID, OUT3, false, true><<<(N + 31) / 32, 256, 0, stream>>>(bufB, W3, nullptr, dinv, bufA, N);
    gatherp_kernel<32, true><<<NB, 256, 0, stream>>>((const __half*)bufA, dinv, gp32, ebuf, b3, bufB, N);

    // ---- pool + head ----
    pool_kernel<<<256, 256, 0, stream>>>(bufB, batch, N, pool);
    head_kernel<<<1, 256, 0, stream>>>(pool, Wh1, bh1, Wh2, bh2, out);
}